// Round 14
// baseline (594.565 us; speedup 1.0000x reference)
//
#include <hip/hip_runtime.h>
#include <hip/hip_bf16.h>
#include <math.h>

#define TOKENS 8192
#define DMODEL 1024
#define DFF    4096
#define NEXP   8
#define ESTRIDE   8448    // per-expert token-list stride (8320 pad + 128 overhang)
#define MAX_SLOTS 72      // 256-row tiles: sum ceil(c_e/256) <= 64 + 8
#define BK 64

typedef __bf16 bf16;
typedef bf16  bf16x4 __attribute__((ext_vector_type(4)));
typedef bf16  bf16x8 __attribute__((ext_vector_type(8)));
typedef float f32x4  __attribute__((ext_vector_type(4)));

__device__ __forceinline__ void gload16(const bf16* g, bf16* l) {
    __builtin_amdgcn_global_load_lds(
        (const __attribute__((address_space(1))) void*)g,
        (__attribute__((address_space(3))) void*)l,
        16, 0, 0);
}

// ---------------- gating: one wave/token; emits xb + topk (NO atomics) ------
__global__ __launch_bounds__(256) void gate_kernel(
    const float* __restrict__ x, const float* __restrict__ gw, const float* __restrict__ gb,
    int2* __restrict__ topk_i, float2* __restrict__ topk_p, bf16* __restrict__ xb)
{
    int wid  = (blockIdx.x * blockDim.x + threadIdx.x) >> 6;
    int lane = threadIdx.x & 63;
    if (wid >= TOKENS) return;
    const float* xr = x + (size_t)wid * DMODEL;
    bf16* xbr = xb + (size_t)wid * DMODEL;
    float a0=0,a1=0,a2=0,a3=0,a4=0,a5=0,a6=0,a7=0;
    #pragma unroll
    for (int i = 0; i < 4; ++i) {
        int cq = i*256 + lane*4;
        float4 xv = *(const float4*)(xr + cq);
        bf16x4 xc = { (bf16)xv.x, (bf16)xv.y, (bf16)xv.z, (bf16)xv.w };
        *(bf16x4*)(xbr + cq) = xc;
        #pragma unroll
        for (int j = 0; j < 4; ++j) {
            float xe = (j==0)?xv.x:(j==1)?xv.y:(j==2)?xv.z:xv.w;
            const float4* g = (const float4*)(gw + (size_t)(cq + j) * NEXP);
            float4 g0 = g[0], g1 = g[1];
            a0 += xe * g0.x; a1 += xe * g0.y; a2 += xe * g0.z; a3 += xe * g0.w;
            a4 += xe * g1.x; a5 += xe * g1.y; a6 += xe * g1.z; a7 += xe * g1.w;
        }
    }
    #pragma unroll
    for (int off = 32; off; off >>= 1) {
        a0 += __shfl_xor(a0, off); a1 += __shfl_xor(a1, off);
        a2 += __shfl_xor(a2, off); a3 += __shfl_xor(a3, off);
        a4 += __shfl_xor(a4, off); a5 += __shfl_xor(a5, off);
        a6 += __shfl_xor(a6, off); a7 += __shfl_xor(a7, off);
    }
    if (lane == 0) {
        float l[NEXP] = { a0+gb[0], a1+gb[1], a2+gb[2], a3+gb[3],
                          a4+gb[4], a5+gb[5], a6+gb[6], a7+gb[7] };
        float m = l[0];
        #pragma unroll
        for (int e = 1; e < NEXP; ++e) m = fmaxf(m, l[e]);
        float p[NEXP], s = 0.f;
        #pragma unroll
        for (int e = 0; e < NEXP; ++e) { p[e] = expf(l[e] - m); s += p[e]; }
        float inv = 1.0f / s;
        int i1 = 0; float b1v = p[0];
        #pragma unroll
        for (int e = 1; e < NEXP; ++e) if (p[e] > b1v) { b1v = p[e]; i1 = e; }
        int i2 = -1; float b2v = -1.f;
        #pragma unroll
        for (int e = 0; e < NEXP; ++e) if (e != i1 && p[e] > b2v) { b2v = p[e]; i2 = e; }
        topk_i[wid] = make_int2(i1, i2);
        topk_p[wid] = make_float2(b1v * inv, b2v * inv);
    }
}

// ---------------- ballot compaction: one wave per expert, zero contention ---
__global__ __launch_bounds__(64) void compact_kernel(
    const int2* __restrict__ topk_i, const float2* __restrict__ topk_p,
    int* __restrict__ counts, int* __restrict__ token_ids, float* __restrict__ pair_p)
{
    int e = blockIdx.x;                        // 0..7
    int lane = threadIdx.x;
    int base = 0;
    for (int it = 0; it < TOKENS/64; ++it) {
        int t = it*64 + lane;
        int2 ki = topk_i[t];
        bool hit = (ki.x == e) || (ki.y == e);
        int which = (ki.y == e) ? 1 : 0;
        unsigned long long m = __ballot(hit);
        if (hit) {
            int idx = base + __popcll(m & ((1ull << lane) - 1ull));
            float2 kp = topk_p[t];
            token_ids[e*ESTRIDE + idx] = t | (which << 13);
            pair_p   [e*ESTRIDE + idx] = which ? kp.y : kp.x;
        }
        base += __popcll(m);
    }
    if (lane == 0) counts[e] = base;
}

// ---------------- routing tables (256-row tiles over 128-padded h segments) -
__global__ void build_slots(const int* __restrict__ counts, int* n_slots,
                            int* slot_e, int* slot_row0, int* slot_gbase)
{
    __shared__ int sc[8], spb[9], stb[9];
    int t = threadIdx.x;                       // 128 threads, 1 block
    if (t < 8) sc[t] = counts[t];
    __syncthreads();
    if (t == 0) {
        int pb = 0, tb = 0;
        for (int e = 0; e < NEXP; ++e) {
            spb[e] = pb; stb[e] = tb;
            pb += ((sc[e] + 127) >> 7) << 7;   // compact 128-padded h bases
            tb += (sc[e] + 255) >> 8;
        }
        spb[8] = pb; stb[8] = tb;
        *n_slots = tb;
    }
    __syncthreads();
    if (t < stb[8]) { int e = 0; while (t >= stb[e+1]) ++e;
        slot_e[t] = e; slot_row0[t] = (t - stb[e]) << 8; slot_gbase[t] = spb[e]; }
}

// ---------------- fp32 [E][R][C] -> bf16 [E][C][R], 64x64, vectorized -------
__global__ __launch_bounds__(256) void transpose_cvt(
    const float* __restrict__ src, bf16* __restrict__ dst, int R, int C)
{
    __shared__ bf16 tile[64 * 72];
    int e = blockIdx.z;
    int c0 = blockIdx.x * 64, r0 = blockIdx.y * 64;
    const float* s = src + (size_t)e * R * C;
    bf16* d = dst + (size_t)e * R * C;
    int t = threadIdx.x;
    {
        int r = t >> 2, q = t & 3;
        const float4* sp = (const float4*)(s + (size_t)(r0 + r) * C + c0 + q * 16);
        float4 v0 = sp[0], v1 = sp[1], v2 = sp[2], v3 = sp[3];
        bf16x8 p0, p1;
        p0[0]=(bf16)v0.x; p0[1]=(bf16)v0.y; p0[2]=(bf16)v0.z; p0[3]=(bf16)v0.w;
        p0[4]=(bf16)v1.x; p0[5]=(bf16)v1.y; p0[6]=(bf16)v1.z; p0[7]=(bf16)v1.w;
        p1[0]=(bf16)v2.x; p1[1]=(bf16)v2.y; p1[2]=(bf16)v2.z; p1[3]=(bf16)v2.w;
        p1[4]=(bf16)v3.x; p1[5]=(bf16)v3.y; p1[6]=(bf16)v3.z; p1[7]=(bf16)v3.w;
        bf16* w = tile + r * 72 + (q ^ (r >> 4)) * 16;
        *(bf16x8*)w = p0; *(bf16x8*)(w + 8) = p1;
    }
    __syncthreads();
    {
        int c = t >> 2, rq = t & 3;
        int gc = c >> 4, cl = c & 15;
        bf16x8 q0, q1;
        #pragma unroll
        for (int k = 0; k < 8; ++k) {
            q0[k] = tile[(rq*16 + k) * 72 + (gc ^ rq) * 16 + cl];
            q1[k] = tile[(rq*16 + 8 + k) * 72 + (gc ^ rq) * 16 + cl];
        }
        bf16* dp = d + (size_t)(c0 + c) * R + r0 + rq * 16;
        *(bf16x8*)dp = q0;
        *(bf16x8*)(dp + 8) = q1;
    }
}

// ---------------- GEMM1: 256x256 8-wave merged-4-phase core (r13 verbatim) --
__global__ __launch_bounds__(512, 2) void moe_gemm1(
    const bf16* __restrict__ Xb, const bf16* __restrict__ Bt,
    const float* __restrict__ bias, bf16* __restrict__ Hout,
    const int* __restrict__ token_ids,
    const int* __restrict__ slot_e, const int* __restrict__ slot_row0,
    const int* __restrict__ slot_gbase, const int* __restrict__ n_slots,
    const int* __restrict__ counts)
{
    constexpr int K = DMODEL, N = DFF, NJT = N / 256, NT = K / BK, NITER = NT / 2;

    int nwg = gridDim.x, bid = blockIdx.x;
    int wid = (bid & 7) * (nwg >> 3) + (bid >> 3);
    int slot = wid / NJT;
    if (slot >= *n_slots) return;
    int jt = wid % NJT;
    int e = slot_e[slot], row0 = slot_row0[slot], gbase = slot_gbase[slot];
    int cnt = counts[e];
    int pad_e = (cnt + 127) & ~127;
    int tlb = e * ESTRIDE;

    __shared__ __align__(16) bf16 shm[65536];

    int t = threadIdx.x, lane = t & 63, wv = t >> 6;
    int wm = wv >> 2, wn = wv & 3;
    int lr = lane & 15, kq = lane >> 4;
    int bh = wn >> 1, bro = (wn & 1) * 64;

    int aoff[2][2]; int boff[2][2];
    const bf16* Bbase = Bt + (size_t)e * N * K;
    int g8 = ((lane & 7) ^ (lane >> 3)) * 8;
    #pragma unroll
    for (int h = 0; h < 2; ++h)
        #pragma unroll
        for (int q = 0; q < 2; ++q) {
            int rloc = h*128 + wv*16 + q*8 + (lane >> 3);
            int tok = token_ids[tlb + row0 + rloc] & 0x1FFF;
            aoff[h][q] = tok * DMODEL + g8;
            boff[h][q] = (jt*256 + rloc) * K + g8;
        }

    f32x4 acc[8][4] = {};
    bf16x8 breg[4][2];

    #define STAGE_A(S, H, T) do { int _t = ((T) < NT ? (T) : 0) * BK;                   \
        gload16(Xb + aoff[H][0] + _t, shm + (((S)*2+(H))*128 + wv*16    ) * BK);        \
        gload16(Xb + aoff[H][1] + _t, shm + (((S)*2+(H))*128 + wv*16 + 8) * BK); } while(0)
    #define STAGE_B(S, H, T) do { int _t = ((T) < NT ? (T) : 0) * BK;                           \
        gload16(Bbase + boff[H][0] + _t, shm + 32768 + (((S)*2+(H))*128 + wv*16    ) * BK);     \
        gload16(Bbase + boff[H][1] + _t, shm + 32768 + (((S)*2+(H))*128 + wv*16 + 8) * BK); } while(0)

    STAGE_A(0,0,0); STAGE_A(0,1,0); STAGE_B(0,0,0); STAGE_B(0,1,0);
    STAGE_B(1,0,1); STAGE_B(1,1,1);
    asm volatile("s_waitcnt vmcnt(4)" ::: "memory");
    __builtin_amdgcn_s_barrier();

    #define LOAD_A(S, Q)                                                             \
        _Pragma("unroll") for (int mi = 0; mi < 2; ++mi)                             \
            _Pragma("unroll") for (int kk = 0; kk < 2; ++kk)                         \
                areg[mi][kk] = *(const bf16x8*)(shm +                                \
                    (((S)*2+wm)*128 + ((Q)*2+mi)*16 + lr) * BK +                     \
                    ((kk*4+kq) ^ (lr & 7)) * 8);
    #define MFMA_Q(Q)                                                                \
        __builtin_amdgcn_s_setprio(1);                                               \
        _Pragma("unroll") for (int mi = 0; mi < 2; ++mi)                             \
            _Pragma("unroll") for (int n = 0; n < 4; ++n)                            \
                _Pragma("unroll") for (int kk = 0; kk < 2; ++kk)                     \
                    acc[(Q)*2+mi][n] = __builtin_amdgcn_mfma_f32_16x16x32_bf16(      \
                        areg[mi][kk], breg[n][kk], acc[(Q)*2+mi][n], 0, 0, 0);       \
        __builtin_amdgcn_s_setprio(0);

    #define PHASE2(S, Q2, STAGE_CODE, DO_WAIT)                                       \
    {                                                                                \
        bf16x8 areg[2][2];                                                           \
        if ((Q2) == 0) {                                                             \
            _Pragma("unroll") for (int n = 0; n < 4; ++n)                            \
                _Pragma("unroll") for (int kk = 0; kk < 2; ++kk)                     \
                    breg[n][kk] = *(const bf16x8*)(shm + 32768 +                     \
                        (((S)*2+bh)*128 + bro + n*16 + lr) * BK +                    \
                        ((kk*4+kq) ^ (lr & 7)) * 8);                                 \
        }                                                                            \
        LOAD_A(S, (Q2)*2)                                                            \
        STAGE_CODE;                                                                  \
        asm volatile("" ::: "memory");                                               \
        __builtin_amdgcn_s_barrier();                                                \
        MFMA_Q((Q2)*2)                                                               \
        LOAD_A(S, (Q2)*2+1)                                                          \
        MFMA_Q((Q2)*2+1)                                                             \
        if (DO_WAIT) asm volatile("s_waitcnt vmcnt(4)" ::: "memory");                \
        asm volatile("" ::: "memory");                                               \
        __builtin_amdgcn_s_barrier();                                                \
    }

    for (int i = 0; i < NITER; ++i) {
        int TO = 2*i+1, TE2 = 2*i+2, TO2 = 2*i+3;
        PHASE2(0, 0, { STAGE_A(1,0,TO);  STAGE_A(1,1,TO);  }, 0)
        PHASE2(0, 1, { STAGE_B(0,0,TE2); STAGE_B(0,1,TE2); }, 1)
        PHASE2(1, 0, { STAGE_A(0,0,TE2); STAGE_A(0,1,TE2); }, 0)
        PHASE2(1, 1, { STAGE_B(1,0,TO2); STAGE_B(1,1,TO2); }, 1)
    }
    asm volatile("s_waitcnt vmcnt(0)" ::: "memory");
    #undef PHASE2
    #undef MFMA_Q
    #undef LOAD_A
    #undef STAGE_A
    #undef STAGE_B

    int lro = kq * 4;
    float bv[4];
    #pragma unroll
    for (int n = 0; n < 4; ++n)
        bv[n] = bias[e * DFF + jt*256 + wn*64 + n*16 + lr];
    #pragma unroll
    for (int m = 0; m < 8; ++m)
        #pragma unroll
        for (int reg = 0; reg < 4; ++reg) {
            int rl = wm*128 + m*16 + lro + reg;
            if (row0 + rl < pad_e) {
                size_t hrow = (size_t)(gbase + row0 + rl);
                #pragma unroll
                for (int n = 0; n < 4; ++n) {
                    int col = jt*256 + wn*64 + n*16 + lr;
                    float v = acc[m][n][reg] + bv[n];
                    v = v / (1.0f + __expf(-v));       // silu
                    __builtin_nontemporal_store((bf16)v, &Hout[hrow * DFF + col]);
                }
            }
        }
}

// ---------------- GEMM2: 256(M)x256(N), KSPL=2, bf16 partials, no atomics ---
// Traffic probe: (256+256)xK staging halves bytes/FLOP vs 128-N tiles:
// 1.06 GB total staged (was 1.58). 2-slot dbuf, 8 gloads/wave/tile, vmcnt(8).
// pbuf row (tok*4 + which*2 + split) = bf16 partial; nt-stores, one writer.
__global__ __launch_bounds__(512, 2) void moe_gemm2(
    const bf16* __restrict__ Ah, const bf16* __restrict__ Bt,
    const float* __restrict__ bias, bf16* __restrict__ pbuf,
    const int* __restrict__ token_ids, const float* __restrict__ pair_p,
    const int* __restrict__ slot_e, const int* __restrict__ slot_row0,
    const int* __restrict__ slot_gbase, const int* __restrict__ n_slots,
    const int* __restrict__ counts)
{
    constexpr int K = DFF, N = DMODEL, NJT = N / 256;
    constexpr int KSPL = 2, KCH = K / KSPL, NT = KCH / BK;   // NT=32

    int nwg = gridDim.x, bid = blockIdx.x;
    int wid = (bid & 7) * (nwg >> 3) + (bid >> 3);
    int slot = wid / (NJT * KSPL);
    if (slot >= *n_slots) return;
    int rem = wid % (NJT * KSPL);
    int jt = rem / KSPL, split = rem % KSPL;
    int kbase = split * KCH;
    int e = slot_e[slot], row0 = slot_row0[slot], gbase = slot_gbase[slot];
    int cnt = counts[e];
    int tlb = e * ESTRIDE;

    __shared__ __align__(16) bf16 shm[65536];   // A: 2x16384 @0; B: 2x16384 @32768

    int t = threadIdx.x, lane = t & 63, wv = t >> 6;
    int wm = wv >> 2, wn = wv & 3;              // 2M(128) x 4N(64) waves
    int lr = lane & 15, kq = lane >> 4;
    int g8 = ((lane & 7) ^ (lane >> 3)) * 8;

    int aoff[4], boff[4];
    const bf16* Bbase = Bt + (size_t)e * N * K;
    #pragma unroll
    for (int q = 0; q < 4; ++q) {
        int rloc = wv*32 + q*8 + (lane >> 3);           // 0..255
        aoff[q] = (gbase + row0 + rloc) * DFF + kbase + g8;
        boff[q] = (jt*256 + rloc) * K + kbase + g8;
    }

    f32x4 acc[8][4] = {};

    #define ST2(S, T) do { int _t = ((T) < NT ? (T) : 0) * BK;                        \
        _Pragma("unroll") for (int q = 0; q < 4; ++q) {                               \
            gload16(Ah + aoff[q] + _t, shm + (S)*16384 + (wv*32 + q*8)*BK);           \
            gload16(Bbase + boff[q] + _t, shm + 32768 + (S)*16384 + (wv*32+q*8)*BK); }\
        } while (0)

    ST2(0, 0);
    for (int tt = 0; tt < NT; ++tt) {
        int cs = tt & 1;
        ST2(cs ^ 1, tt + 1);                     // junk re-stage of tile 0 at tail
        asm volatile("s_waitcnt vmcnt(8)" ::: "memory");   // own tile-tt 8 loads landed
        __builtin_amdgcn_s_barrier();
        bf16x8 breg[4][2];
        #pragma unroll
        for (int n = 0; n < 4; ++n)
            #pragma unroll
            for (int kk = 0; kk < 2; ++kk)
                breg[n][kk] = *(const bf16x8*)(shm + 32768 + cs*16384 +
                    (wn*64 + n*16 + lr)*BK + ((kk*4+kq) ^ (lr & 7))*8);
        #pragma unroll
        for (int Q = 0; Q < 4; ++Q) {
            bf16x8 areg[2][2];
            #pragma unroll
            for (int mi = 0; mi < 2; ++mi)
                #pragma unroll
                for (int kk = 0; kk < 2; ++kk)
                    areg[mi][kk] = *(const bf16x8*)(shm + cs*16384 +
                        (wm*128 + (Q*2+mi)*16 + lr)*BK + ((kk*4+kq) ^ (lr & 7))*8);
            __builtin_amdgcn_s_setprio(1);
            #pragma unroll
            for (int mi = 0; mi < 2; ++mi)
                #pragma unroll
                for (int n = 0; n < 4; ++n)
                    #pragma unroll
                    for (int kk = 0; kk < 2; ++kk)
                        acc[Q*2+mi][n] = __builtin_amdgcn_mfma_f32_16x16x32_bf16(
                            areg[mi][kk], breg[n][kk], acc[Q*2+mi][n], 0, 0, 0);
            __builtin_amdgcn_s_setprio(0);
        }
        asm volatile("" ::: "memory");
        __builtin_amdgcn_s_barrier();
    }
    asm volatile("s_waitcnt vmcnt(0)" ::: "memory");
    #undef ST2

    float bv[4];
    #pragma unroll
    for (int n = 0; n < 4; ++n)
        bv[n] = (split == 0) ? bias[e * DMODEL + jt*256 + wn*64 + n*16 + lr] : 0.0f;
    #pragma unroll
    for (int m = 0; m < 8; ++m)
        #pragma unroll
        for (int reg = 0; reg < 4; ++reg) {
            int rl = wm*128 + m*16 + kq*4 + reg;
            if (row0 + rl < cnt) {
                int pr = tlb + row0 + rl;
                int tw = token_ids[pr];
                int tok = tw & 0x1FFF, wh = (tw >> 13) & 1;
                float p = pair_p[pr];
                bf16* dst = pbuf + ((size_t)(tok*4 + wh*2 + split)) * DMODEL;
                #pragma unroll
                for (int n = 0; n < 4; ++n) {
                    int col = jt*256 + wn*64 + n*16 + lr;
                    __builtin_nontemporal_store((bf16)(p * (acc[m][n][reg] + bv[n])), &dst[col]);
                }
            }
        }
}

// ---------------- combine: out[tok] = sum of 4 bf16 partial rows ------------
__global__ __launch_bounds__(256) void combine_kernel(
    const bf16* __restrict__ pbuf, float* __restrict__ out)
{
    int wid  = (blockIdx.x * 256 + threadIdx.x) >> 6;   // token
    int lane = threadIdx.x & 63;
    const bf16* pr = pbuf + (size_t)wid * 4 * DMODEL;
    float* o = out + (size_t)wid * DMODEL;
    #pragma unroll
    for (int i = 0; i < 2; ++i) {
        int c = (i*64 + lane) * 8;                      // 8 cols per lane-step
        bf16x8 v0 = *(const bf16x8*)(pr + c);
        bf16x8 v1 = *(const bf16x8*)(pr + DMODEL + c);
        bf16x8 v2 = *(const bf16x8*)(pr + 2*DMODEL + c);
        bf16x8 v3 = *(const bf16x8*)(pr + 3*DMODEL + c);
        f32x4 r0, r1;
        #pragma unroll
        for (int k = 0; k < 4; ++k)
            r0[k] = (float)v0[k] + (float)v1[k] + (float)v2[k] + (float)v3[k];
        #pragma unroll
        for (int k = 0; k < 4; ++k)
            r1[k] = (float)v0[4+k] + (float)v1[4+k] + (float)v2[4+k] + (float)v3[4+k];
        *(f32x4*)(o + c) = r0;
        *(f32x4*)(o + c + 4) = r1;
    }
}

// ---------------- launch ----------------
extern "C" void kernel_launch(void* const* d_in, const int* in_sizes, int n_in,
                              void* d_out, int out_size, void* d_ws, size_t ws_size,
                              hipStream_t stream)
{
    const float* x  = (const float*)d_in[0];
    const float* gw = (const float*)d_in[1];
    const float* gb = (const float*)d_in[2];
    const float* w1 = (const float*)d_in[3];
    const float* b1 = (const float*)d_in[4];
    const float* w2 = (const float*)d_in[5];
    const float* b2 = (const float*)d_in[6];
    float* out = (float*)d_out;

    const size_t W1T_OFF = 0;                               // w1t, then bf16 pbuf (64 MiB)
    const size_t W2T_OFF = 67108864;                        // xb, then w2t
    const size_t H_OFF   = 134217728;                       // h (17408 rows used)
    const size_t S_OFF   = H_OFF + (size_t)17408 * DFF * 2; // 276824064: routing
    const size_t WS_NEEDED = S_OFF + 4096 + 2*(NEXP*ESTRIDE*4) + 2*(TOKENS*8);  // ~277.5MB
    if (ws_size < WS_NEEDED) return;                        // fail clean

    char* ws = (char*)d_ws;
    bf16*  w1t  = (bf16*)(ws + W1T_OFF);
    bf16*  pbuf = (bf16*)(ws + W1T_OFF);        // alias: pbuf live only after gemm1 (32768x1024 bf16)
    bf16*  w2t  = (bf16*)(ws + W2T_OFF);
    bf16*  xb   = (bf16*)(ws + W2T_OFF);        // alias: xb dead after gemm1
    bf16*  h    = (bf16*)(ws + H_OFF);
    char*  S    = ws + S_OFF;
    int*   counts    = (int*)(S + 0);
    int*   n_slots   = (int*)(S + 64);
    int*   slot_e    = (int*)(S + 128);
    int*   slot_row0 = (int*)(S + 512);
    int*   slot_gbase= (int*)(S + 896);
    int*   token_ids = (int*)(S + 4096);
    float* pair_p    = (float*)(S + 4096 + NEXP*ESTRIDE*4);
    int2*  topk_i    = (int2*)(S + 4096 + 2*(NEXP*ESTRIDE*4));
    float2* topk_p   = (float2*)(S + 4096 + 2*(NEXP*ESTRIDE*4) + TOKENS*8);

    transpose_cvt<<<dim3(DFF/64, DMODEL/64, NEXP), dim3(256), 0, stream>>>(w1, w1t, DMODEL, DFF);

    gate_kernel<<<TOKENS * 64 / 256, 256, 0, stream>>>(x, gw, gb, topk_i, topk_p, xb);
    compact_kernel<<<NEXP, 64, 0, stream>>>(topk_i, topk_p, counts, token_ids, pair_p);
    build_slots<<<1, 128, 0, stream>>>(counts, n_slots, slot_e, slot_row0, slot_gbase);

    moe_gemm1<<<MAX_SLOTS * (DFF/256), 512, 0, stream>>>(
        xb, w1t, b1, h, token_ids, slot_e, slot_row0, slot_gbase, n_slots, counts);

    // w2 transpose AFTER gemm1 so w2t can alias xb
    transpose_cvt<<<dim3(DMODEL/64, DFF/64, NEXP), dim3(256), 0, stream>>>(w2, w2t, DFF, DMODEL);

    moe_gemm2<<<MAX_SLOTS * (DMODEL/256) * 2, 512, 0, stream>>>(
        h, w2t, b2, pbuf, token_ids, pair_p, slot_e, slot_row0, slot_gbase, n_slots, counts);

    combine_kernel<<<TOKENS * 64 / 256, 256, 0, stream>>>(pbuf, out);
}

// Round 15
// 577.047 us; speedup vs baseline: 1.0304x; 1.0304x over previous
//
#include <hip/hip_runtime.h>
#include <hip/hip_bf16.h>
#include <math.h>

#define TOKENS 8192
#define DMODEL 1024
#define DFF    4096
#define NEXP   8
#define ESTRIDE   8448    // per-expert token-list stride (8320 pad + 128 overhang)
#define MAX_SLOTS 72      // 256-row tiles: sum ceil(c_e/256) <= 64 + 8
#define BK 64

typedef __bf16 bf16;
typedef bf16  bf16x4 __attribute__((ext_vector_type(4)));
typedef bf16  bf16x8 __attribute__((ext_vector_type(8)));
typedef float f32x4  __attribute__((ext_vector_type(4)));

__device__ __forceinline__ void gload16(const bf16* g, bf16* l) {
    __builtin_amdgcn_global_load_lds(
        (const __attribute__((address_space(1))) void*)g,
        (__attribute__((address_space(3))) void*)l,
        16, 0, 0);
}

// ---------------- gating: one wave/token; emits xb + topk (NO atomics) ------
__global__ __launch_bounds__(256) void gate_kernel(
    const float* __restrict__ x, const float* __restrict__ gw, const float* __restrict__ gb,
    int2* __restrict__ topk_i, float2* __restrict__ topk_p, bf16* __restrict__ xb)
{
    int wid  = (blockIdx.x * blockDim.x + threadIdx.x) >> 6;
    int lane = threadIdx.x & 63;
    if (wid >= TOKENS) return;
    const float* xr = x + (size_t)wid * DMODEL;
    bf16* xbr = xb + (size_t)wid * DMODEL;
    float a0=0,a1=0,a2=0,a3=0,a4=0,a5=0,a6=0,a7=0;
    #pragma unroll
    for (int i = 0; i < 4; ++i) {
        int cq = i*256 + lane*4;
        float4 xv = *(const float4*)(xr + cq);
        bf16x4 xc = { (bf16)xv.x, (bf16)xv.y, (bf16)xv.z, (bf16)xv.w };
        *(bf16x4*)(xbr + cq) = xc;
        #pragma unroll
        for (int j = 0; j < 4; ++j) {
            float xe = (j==0)?xv.x:(j==1)?xv.y:(j==2)?xv.z:xv.w;
            const float4* g = (const float4*)(gw + (size_t)(cq + j) * NEXP);
            float4 g0 = g[0], g1 = g[1];
            a0 += xe * g0.x; a1 += xe * g0.y; a2 += xe * g0.z; a3 += xe * g0.w;
            a4 += xe * g1.x; a5 += xe * g1.y; a6 += xe * g1.z; a7 += xe * g1.w;
        }
    }
    #pragma unroll
    for (int off = 32; off; off >>= 1) {
        a0 += __shfl_xor(a0, off); a1 += __shfl_xor(a1, off);
        a2 += __shfl_xor(a2, off); a3 += __shfl_xor(a3, off);
        a4 += __shfl_xor(a4, off); a5 += __shfl_xor(a5, off);
        a6 += __shfl_xor(a6, off); a7 += __shfl_xor(a7, off);
    }
    if (lane == 0) {
        float l[NEXP] = { a0+gb[0], a1+gb[1], a2+gb[2], a3+gb[3],
                          a4+gb[4], a5+gb[5], a6+gb[6], a7+gb[7] };
        float m = l[0];
        #pragma unroll
        for (int e = 1; e < NEXP; ++e) m = fmaxf(m, l[e]);
        float p[NEXP], s = 0.f;
        #pragma unroll
        for (int e = 0; e < NEXP; ++e) { p[e] = expf(l[e] - m); s += p[e]; }
        float inv = 1.0f / s;
        int i1 = 0; float b1v = p[0];
        #pragma unroll
        for (int e = 1; e < NEXP; ++e) if (p[e] > b1v) { b1v = p[e]; i1 = e; }
        int i2 = -1; float b2v = -1.f;
        #pragma unroll
        for (int e = 0; e < NEXP; ++e) if (e != i1 && p[e] > b2v) { b2v = p[e]; i2 = e; }
        topk_i[wid] = make_int2(i1, i2);
        topk_p[wid] = make_float2(b1v * inv, b2v * inv);
    }
}

// ---------------- ballot compaction: one wave per expert, zero contention ---
__global__ __launch_bounds__(64) void compact_kernel(
    const int2* __restrict__ topk_i, const float2* __restrict__ topk_p,
    int* __restrict__ counts, int* __restrict__ token_ids, float* __restrict__ pair_p)
{
    int e = blockIdx.x;                        // 0..7
    int lane = threadIdx.x;
    int base = 0;
    for (int it = 0; it < TOKENS/64; ++it) {
        int t = it*64 + lane;
        int2 ki = topk_i[t];
        bool hit = (ki.x == e) || (ki.y == e);
        int which = (ki.y == e) ? 1 : 0;
        unsigned long long m = __ballot(hit);
        if (hit) {
            int idx = base + __popcll(m & ((1ull << lane) - 1ull));
            float2 kp = topk_p[t];
            token_ids[e*ESTRIDE + idx] = t | (which << 13);
            pair_p   [e*ESTRIDE + idx] = which ? kp.y : kp.x;
        }
        base += __popcll(m);
    }
    if (lane == 0) counts[e] = base;
}

// ---------------- routing tables (256-row tiles over 128-padded h segments) -
__global__ void build_slots(const int* __restrict__ counts, int* n_slots,
                            int* slot_e, int* slot_row0, int* slot_gbase)
{
    __shared__ int sc[8], spb[9], stb[9];
    int t = threadIdx.x;                       // 128 threads, 1 block
    if (t < 8) sc[t] = counts[t];
    __syncthreads();
    if (t == 0) {
        int pb = 0, tb = 0;
        for (int e = 0; e < NEXP; ++e) {
            spb[e] = pb; stb[e] = tb;
            pb += ((sc[e] + 127) >> 7) << 7;   // compact 128-padded h bases
            tb += (sc[e] + 255) >> 8;
        }
        spb[8] = pb; stb[8] = tb;
        *n_slots = tb;
    }
    __syncthreads();
    if (t < stb[8]) { int e = 0; while (t >= stb[e+1]) ++e;
        slot_e[t] = e; slot_row0[t] = (t - stb[e]) << 8; slot_gbase[t] = spb[e]; }
}

// ---------------- fp32 [E][R][C] -> bf16 [E][C][R], 64x64, vectorized -------
__global__ __launch_bounds__(256) void transpose_cvt(
    const float* __restrict__ src, bf16* __restrict__ dst, int R, int C)
{
    __shared__ bf16 tile[64 * 72];
    int e = blockIdx.z;
    int c0 = blockIdx.x * 64, r0 = blockIdx.y * 64;
    const float* s = src + (size_t)e * R * C;
    bf16* d = dst + (size_t)e * R * C;
    int t = threadIdx.x;
    {
        int r = t >> 2, q = t & 3;
        const float4* sp = (const float4*)(s + (size_t)(r0 + r) * C + c0 + q * 16);
        float4 v0 = sp[0], v1 = sp[1], v2 = sp[2], v3 = sp[3];
        bf16x8 p0, p1;
        p0[0]=(bf16)v0.x; p0[1]=(bf16)v0.y; p0[2]=(bf16)v0.z; p0[3]=(bf16)v0.w;
        p0[4]=(bf16)v1.x; p0[5]=(bf16)v1.y; p0[6]=(bf16)v1.z; p0[7]=(bf16)v1.w;
        p1[0]=(bf16)v2.x; p1[1]=(bf16)v2.y; p1[2]=(bf16)v2.z; p1[3]=(bf16)v2.w;
        p1[4]=(bf16)v3.x; p1[5]=(bf16)v3.y; p1[6]=(bf16)v3.z; p1[7]=(bf16)v3.w;
        bf16* w = tile + r * 72 + (q ^ (r >> 4)) * 16;
        *(bf16x8*)w = p0; *(bf16x8*)(w + 8) = p1;
    }
    __syncthreads();
    {
        int c = t >> 2, rq = t & 3;
        int gc = c >> 4, cl = c & 15;
        bf16x8 q0, q1;
        #pragma unroll
        for (int k = 0; k < 8; ++k) {
            q0[k] = tile[(rq*16 + k) * 72 + (gc ^ rq) * 16 + cl];
            q1[k] = tile[(rq*16 + 8 + k) * 72 + (gc ^ rq) * 16 + cl];
        }
        bf16* dp = d + (size_t)(c0 + c) * R + r0 + rq * 16;
        *(bf16x8*)dp = q0;
        *(bf16x8*)(dp + 8) = q1;
    }
}

// ---------------- GEMM1: 256x256 8-wave merged-4-phase core -----------------
__global__ __launch_bounds__(512, 2) void moe_gemm1(
    const bf16* __restrict__ Xb, const bf16* __restrict__ Bt,
    const float* __restrict__ bias, bf16* __restrict__ Hout,
    const int* __restrict__ token_ids,
    const int* __restrict__ slot_e, const int* __restrict__ slot_row0,
    const int* __restrict__ slot_gbase, const int* __restrict__ n_slots,
    const int* __restrict__ counts)
{
    constexpr int K = DMODEL, N = DFF, NJT = N / 256, NT = K / BK, NITER = NT / 2;

    int nwg = gridDim.x, bid = blockIdx.x;
    int wid = (bid & 7) * (nwg >> 3) + (bid >> 3);
    int slot = wid / NJT;
    if (slot >= *n_slots) return;
    int jt = wid % NJT;
    int e = slot_e[slot], row0 = slot_row0[slot], gbase = slot_gbase[slot];
    int cnt = counts[e];
    int pad_e = (cnt + 127) & ~127;
    int tlb = e * ESTRIDE;

    __shared__ __align__(16) bf16 shm[65536];

    int t = threadIdx.x, lane = t & 63, wv = t >> 6;
    int wm = wv >> 2, wn = wv & 3;
    int lr = lane & 15, kq = lane >> 4;
    int bh = wn >> 1, bro = (wn & 1) * 64;

    int aoff[2][2]; int boff[2][2];
    const bf16* Bbase = Bt + (size_t)e * N * K;
    int g8 = ((lane & 7) ^ (lane >> 3)) * 8;
    #pragma unroll
    for (int h = 0; h < 2; ++h)
        #pragma unroll
        for (int q = 0; q < 2; ++q) {
            int rloc = h*128 + wv*16 + q*8 + (lane >> 3);
            int tok = token_ids[tlb + row0 + rloc] & 0x1FFF;
            aoff[h][q] = tok * DMODEL + g8;
            boff[h][q] = (jt*256 + rloc) * K + g8;
        }

    f32x4 acc[8][4] = {};
    bf16x8 breg[4][2];

    #define STAGE_A(S, H, T) do { int _t = ((T) < NT ? (T) : 0) * BK;                   \
        gload16(Xb + aoff[H][0] + _t, shm + (((S)*2+(H))*128 + wv*16    ) * BK);        \
        gload16(Xb + aoff[H][1] + _t, shm + (((S)*2+(H))*128 + wv*16 + 8) * BK); } while(0)
    #define STAGE_B(S, H, T) do { int _t = ((T) < NT ? (T) : 0) * BK;                           \
        gload16(Bbase + boff[H][0] + _t, shm + 32768 + (((S)*2+(H))*128 + wv*16    ) * BK);     \
        gload16(Bbase + boff[H][1] + _t, shm + 32768 + (((S)*2+(H))*128 + wv*16 + 8) * BK); } while(0)

    STAGE_A(0,0,0); STAGE_A(0,1,0); STAGE_B(0,0,0); STAGE_B(0,1,0);
    STAGE_B(1,0,1); STAGE_B(1,1,1);
    asm volatile("s_waitcnt vmcnt(4)" ::: "memory");
    __builtin_amdgcn_s_barrier();

    #define LOAD_A(S, Q)                                                             \
        _Pragma("unroll") for (int mi = 0; mi < 2; ++mi)                             \
            _Pragma("unroll") for (int kk = 0; kk < 2; ++kk)                         \
                areg[mi][kk] = *(const bf16x8*)(shm +                                \
                    (((S)*2+wm)*128 + ((Q)*2+mi)*16 + lr) * BK +                     \
                    ((kk*4+kq) ^ (lr & 7)) * 8);
    #define MFMA_Q(Q)                                                                \
        __builtin_amdgcn_s_setprio(1);                                               \
        _Pragma("unroll") for (int mi = 0; mi < 2; ++mi)                             \
            _Pragma("unroll") for (int n = 0; n < 4; ++n)                            \
                _Pragma("unroll") for (int kk = 0; kk < 2; ++kk)                     \
                    acc[(Q)*2+mi][n] = __builtin_amdgcn_mfma_f32_16x16x32_bf16(      \
                        areg[mi][kk], breg[n][kk], acc[(Q)*2+mi][n], 0, 0, 0);       \
        __builtin_amdgcn_s_setprio(0);

    #define PHASE2(S, Q2, STAGE_CODE, DO_WAIT)                                       \
    {                                                                                \
        bf16x8 areg[2][2];                                                           \
        if ((Q2) == 0) {                                                             \
            _Pragma("unroll") for (int n = 0; n < 4; ++n)                            \
                _Pragma("unroll") for (int kk = 0; kk < 2; ++kk)                     \
                    breg[n][kk] = *(const bf16x8*)(shm + 32768 +                     \
                        (((S)*2+bh)*128 + bro + n*16 + lr) * BK +                    \
                        ((kk*4+kq) ^ (lr & 7)) * 8);                                 \
        }                                                                            \
        LOAD_A(S, (Q2)*2)                                                            \
        STAGE_CODE;                                                                  \
        asm volatile("" ::: "memory");                                               \
        __builtin_amdgcn_s_barrier();                                                \
        MFMA_Q((Q2)*2)                                                               \
        LOAD_A(S, (Q2)*2+1)                                                          \
        MFMA_Q((Q2)*2+1)                                                             \
        if (DO_WAIT) asm volatile("s_waitcnt vmcnt(4)" ::: "memory");                \
        asm volatile("" ::: "memory");                                               \
        __builtin_amdgcn_s_barrier();                                                \
    }

    for (int i = 0; i < NITER; ++i) {
        int TO = 2*i+1, TE2 = 2*i+2, TO2 = 2*i+3;
        PHASE2(0, 0, { STAGE_A(1,0,TO);  STAGE_A(1,1,TO);  }, 0)
        PHASE2(0, 1, { STAGE_B(0,0,TE2); STAGE_B(0,1,TE2); }, 1)
        PHASE2(1, 0, { STAGE_A(0,0,TE2); STAGE_A(0,1,TE2); }, 0)
        PHASE2(1, 1, { STAGE_B(1,0,TO2); STAGE_B(1,1,TO2); }, 1)
    }
    asm volatile("s_waitcnt vmcnt(0)" ::: "memory");
    #undef PHASE2
    #undef MFMA_Q
    #undef LOAD_A
    #undef STAGE_A
    #undef STAGE_B

    int lro = kq * 4;
    float bv[4];
    #pragma unroll
    for (int n = 0; n < 4; ++n)
        bv[n] = bias[e * DFF + jt*256 + wn*64 + n*16 + lr];
    #pragma unroll
    for (int m = 0; m < 8; ++m)
        #pragma unroll
        for (int reg = 0; reg < 4; ++reg) {
            int rl = wm*128 + m*16 + lro + reg;
            if (row0 + rl < pad_e) {
                size_t hrow = (size_t)(gbase + row0 + rl);
                #pragma unroll
                for (int n = 0; n < 4; ++n) {
                    int col = jt*256 + wn*64 + n*16 + lr;
                    float v = acc[m][n][reg] + bv[n];
                    v = v / (1.0f + __expf(-v));       // silu
                    __builtin_nontemporal_store((bf16)v, &Hout[hrow * DFF + col]);
                }
            }
        }
}

// ---------------- GEMM2: 256(M)x128(N), KSPL=2, bf16 partials, no atomics ---
// Ring-3 depth-2 prefetch, vmcnt(12). Best-measured config (r13: 218.6us).
__global__ __launch_bounds__(512, 2) void moe_gemm2(
    const bf16* __restrict__ Ah, const bf16* __restrict__ Bt,
    const float* __restrict__ bias, bf16* __restrict__ pbuf,
    const int* __restrict__ token_ids, const float* __restrict__ pair_p,
    const int* __restrict__ slot_e, const int* __restrict__ slot_row0,
    const int* __restrict__ slot_gbase, const int* __restrict__ n_slots,
    const int* __restrict__ counts)
{
    constexpr int K = DFF, N = DMODEL, NJT = N / 128;
    constexpr int KSPL = 2, KCH = K / KSPL, NT = KCH / BK;   // NT=32

    int nwg = gridDim.x, bid = blockIdx.x;
    int wid = (bid & 7) * (nwg >> 3) + (bid >> 3);
    int slot = wid / (NJT * KSPL);
    if (slot >= *n_slots) return;
    int rem = wid % (NJT * KSPL);
    int jt = rem / KSPL, split = rem % KSPL;
    int kbase = split * KCH;
    int e = slot_e[slot], row0 = slot_row0[slot], gbase = slot_gbase[slot];
    int cnt = counts[e];
    int tlb = e * ESTRIDE;

    __shared__ __align__(16) bf16 shm[73728];   // A: 3x16384 @0; B: 3x8192 @49152

    int t = threadIdx.x, lane = t & 63, wv = t >> 6;
    int wm4 = wv >> 1, wn2 = wv & 1;
    int lr = lane & 15, kq = lane >> 4;
    int g8 = ((lane & 7) ^ (lane >> 3)) * 8;

    int aoff[4], boff[2];
    const bf16* Bbase = Bt + (size_t)e * N * K;
    #pragma unroll
    for (int q = 0; q < 4; ++q) {
        int rloc = wv*32 + q*8 + (lane >> 3);
        aoff[q] = (gbase + row0 + rloc) * DFF + kbase + g8;
    }
    #pragma unroll
    for (int q = 0; q < 2; ++q) {
        int rloc = wv*16 + q*8 + (lane >> 3);
        boff[q] = (jt*128 + rloc) * K + kbase + g8;
    }

    f32x4 acc[4][4] = {};

    #define ST2(S, T) do { int _t = ((T) < NT ? (T) : 0) * BK;                        \
        _Pragma("unroll") for (int q = 0; q < 4; ++q)                                 \
            gload16(Ah + aoff[q] + _t, shm + (S)*16384 + (wv*32 + q*8)*BK);           \
        _Pragma("unroll") for (int q = 0; q < 2; ++q)                                 \
            gload16(Bbase + boff[q] + _t, shm + 49152 + (S)*8192 + (wv*16 + q*8)*BK); \
        } while (0)

    ST2(0, 0); ST2(1, 1);
    int cs = 0, ps = 2;
    for (int tt = 0; tt < NT; ++tt) {
        ST2(ps, tt + 2);                         // junk re-stage at tail
        asm volatile("s_waitcnt vmcnt(12)" ::: "memory");   // tile tt certified
        __builtin_amdgcn_s_barrier();
        bf16x8 areg[4][2], breg[4][2];
        #pragma unroll
        for (int m = 0; m < 4; ++m)
            #pragma unroll
            for (int kk = 0; kk < 2; ++kk)
                areg[m][kk] = *(const bf16x8*)(shm + cs*16384 +
                    (wm4*64 + m*16 + lr)*BK + ((kk*4+kq) ^ (lr & 7))*8);
        #pragma unroll
        for (int n = 0; n < 4; ++n)
            #pragma unroll
            for (int kk = 0; kk < 2; ++kk)
                breg[n][kk] = *(const bf16x8*)(shm + 49152 + cs*8192 +
                    (wn2*64 + n*16 + lr)*BK + ((kk*4+kq) ^ (lr & 7))*8);
        __builtin_amdgcn_s_setprio(1);
        #pragma unroll
        for (int m = 0; m < 4; ++m)
            #pragma unroll
            for (int n = 0; n < 4; ++n)
                #pragma unroll
                for (int kk = 0; kk < 2; ++kk)
                    acc[m][n] = __builtin_amdgcn_mfma_f32_16x16x32_bf16(
                        areg[m][kk], breg[n][kk], acc[m][n], 0, 0, 0);
        __builtin_amdgcn_s_setprio(0);
        asm volatile("" ::: "memory");
        __builtin_amdgcn_s_barrier();
        cs = (cs == 2) ? 0 : cs + 1;
        ps = (ps == 2) ? 0 : ps + 1;
    }
    asm volatile("s_waitcnt vmcnt(0)" ::: "memory");
    #undef ST2

    float bv[4];
    #pragma unroll
    for (int n = 0; n < 4; ++n)
        bv[n] = (split == 0) ? bias[e * DMODEL + jt*128 + wn2*64 + n*16 + lr] : 0.0f;
    #pragma unroll
    for (int m = 0; m < 4; ++m)
        #pragma unroll
        for (int reg = 0; reg < 4; ++reg) {
            int rl = wm4*64 + m*16 + kq*4 + reg;
            if (row0 + rl < cnt) {
                int pr = tlb + row0 + rl;
                int tw = token_ids[pr];
                int tok = tw & 0x1FFF, wh = (tw >> 13) & 1;
                float p = pair_p[pr];
                bf16* dst = pbuf + ((size_t)(tok*4 + wh*2 + split)) * DMODEL;
                #pragma unroll
                for (int n = 0; n < 4; ++n) {
                    int col = jt*128 + wn2*64 + n*16 + lr;
                    __builtin_nontemporal_store((bf16)(p * (acc[m][n][reg] + bv[n])), &dst[col]);
                }
            }
        }
}

// ---------------- combine: out[tok] = sum of 4 bf16 partial rows ------------
__global__ __launch_bounds__(256) void combine_kernel(
    const bf16* __restrict__ pbuf, float* __restrict__ out)
{
    int wid  = (blockIdx.x * 256 + threadIdx.x) >> 6;   // token
    int lane = threadIdx.x & 63;
    const bf16* pr = pbuf + (size_t)wid * 4 * DMODEL;
    float* o = out + (size_t)wid * DMODEL;
    #pragma unroll
    for (int i = 0; i < 2; ++i) {
        int c = (i*64 + lane) * 8;                      // 8 cols per lane-step
        bf16x8 v0 = *(const bf16x8*)(pr + c);
        bf16x8 v1 = *(const bf16x8*)(pr + DMODEL + c);
        bf16x8 v2 = *(const bf16x8*)(pr + 2*DMODEL + c);
        bf16x8 v3 = *(const bf16x8*)(pr + 3*DMODEL + c);
        f32x4 r0, r1;
        #pragma unroll
        for (int k = 0; k < 4; ++k)
            r0[k] = (float)v0[k] + (float)v1[k] + (float)v2[k] + (float)v3[k];
        #pragma unroll
        for (int k = 0; k < 4; ++k)
            r1[k] = (float)v0[4+k] + (float)v1[4+k] + (float)v2[4+k] + (float)v3[4+k];
        *(f32x4*)(o + c) = r0;
        *(f32x4*)(o + c + 4) = r1;
    }
}

// ---------------- launch ----------------
extern "C" void kernel_launch(void* const* d_in, const int* in_sizes, int n_in,
                              void* d_out, int out_size, void* d_ws, size_t ws_size,
                              hipStream_t stream)
{
    const float* x  = (const float*)d_in[0];
    const float* gw = (const float*)d_in[1];
    const float* gb = (const float*)d_in[2];
    const float* w1 = (const float*)d_in[3];
    const float* b1 = (const float*)d_in[4];
    const float* w2 = (const float*)d_in[5];
    const float* b2 = (const float*)d_in[6];
    float* out = (float*)d_out;

    const size_t W1T_OFF = 0;                               // w1t, then bf16 pbuf (64 MiB)
    const size_t W2T_OFF = 67108864;                        // xb, then w2t
    const size_t H_OFF   = 134217728;                       // h (17408 rows used)
    const size_t S_OFF   = H_OFF + (size_t)17408 * DFF * 2; // 276824064: routing
    const size_t WS_NEEDED = S_OFF + 4096 + 2*(NEXP*ESTRIDE*4) + 2*(TOKENS*8);  // ~277.5MB
    if (ws_size < WS_NEEDED) return;                        // fail clean

    char* ws = (char*)d_ws;
    bf16*  w1t  = (bf16*)(ws + W1T_OFF);
    bf16*  pbuf = (bf16*)(ws + W1T_OFF);        // alias: pbuf live only after gemm1 (32768x1024 bf16)
    bf16*  w2t  = (bf16*)(ws + W2T_OFF);
    bf16*  xb   = (bf16*)(ws + W2T_OFF);        // alias: xb dead after gemm1
    bf16*  h    = (bf16*)(ws + H_OFF);
    char*  S    = ws + S_OFF;
    int*   counts    = (int*)(S + 0);
    int*   n_slots   = (int*)(S + 64);
    int*   slot_e    = (int*)(S + 128);
    int*   slot_row0 = (int*)(S + 512);
    int*   slot_gbase= (int*)(S + 896);
    int*   token_ids = (int*)(S + 4096);
    float* pair_p    = (float*)(S + 4096 + NEXP*ESTRIDE*4);
    int2*  topk_i    = (int2*)(S + 4096 + 2*(NEXP*ESTRIDE*4));
    float2* topk_p   = (float2*)(S + 4096 + 2*(NEXP*ESTRIDE*4) + TOKENS*8);

    transpose_cvt<<<dim3(DFF/64, DMODEL/64, NEXP), dim3(256), 0, stream>>>(w1, w1t, DMODEL, DFF);

    gate_kernel<<<TOKENS * 64 / 256, 256, 0, stream>>>(x, gw, gb, topk_i, topk_p, xb);
    compact_kernel<<<NEXP, 64, 0, stream>>>(topk_i, topk_p, counts, token_ids, pair_p);
    build_slots<<<1, 128, 0, stream>>>(counts, n_slots, slot_e, slot_row0, slot_gbase);

    moe_gemm1<<<MAX_SLOTS * (DFF/256), 512, 0, stream>>>(
        xb, w1t, b1, h, token_ids, slot_e, slot_row0, slot_gbase, n_slots, counts);

    // w2 transpose AFTER gemm1 so w2t can alias xb
    transpose_cvt<<<dim3(DMODEL/64, DFF/64, NEXP), dim3(256), 0, stream>>>(w2, w2t, DFF, DMODEL);

    moe_gemm2<<<MAX_SLOTS * (DMODEL/128) * 2, 512, 0, stream>>>(
        h, w2t, b2, pbuf, token_ids, pair_p, slot_e, slot_row0, slot_gbase, n_slots, counts);

    combine_kernel<<<TOKENS * 64 / 256, 256, 0, stream>>>(pbuf, out);
}